// Round 17
// baseline (45.339 us; speedup 1.0000x reference)
//
#include <hip/hip_runtime.h>

// affine_grid + grid_sample (bilinear, zeros, align_corners=False)
// N=64, C=3, H=345, W=456, fp32.
// Round 17: r15 structure scaled to 32x32 tiles / 512-thread blocks
//           (2 px/thread unchanged) -> per-block overhead amortized 2x;
//           4 blocks x 512 = 2048 thr/CU (100% cap); nontemporal stores.
constexpr int N_ = 64, C_ = 3, H_ = 345, W_ = 456;
constexpr int HW_ = H_ * W_;

constexpr int TW = 32, TH = 32;                // output tile: 1024 px, 2 px/thread
constexpr int TX = 15, TY = 11;                // ceil(456/32), ceil(345/32)
constexpr int TILES = TX * TY;                 // 165
constexpr int CCAP = 52;                       // staged cols / LDS row stride (13 float4)
constexpr int RCAP = 50;                       // staged rows capacity
constexpr int CJ   = 13;                       // float4 granules per row
constexpr int CH_STRIDE = RCAP * CCAP;         // 2600 floats/channel (31200 B total)

typedef __attribute__((ext_vector_type(2))) float f32x2;

__device__ __forceinline__ float ufl(float v) {
    return __int_as_float(__builtin_amdgcn_readfirstlane(__float_as_int(v)));
}

__global__ __launch_bounds__(512) void gs_tiled(
    const float* __restrict__ x,      // [N,3,H,W]
    const float* __restrict__ theta,  // [N,2,3]
    float* __restrict__ out)          // [N,3,H,W]
{
    __shared__ float lds[3 * CH_STRIDE];       // 31200 B -> 4 blocks/CU (thread cap)

    // XCD-affine: batch n -> XCD n%8 only (grid divisible by 8).
    int b    = blockIdx.x;
    int xcd  = b & 7;
    int i    = b >> 3;                 // 0..1319
    int bg   = i / TILES;              // 0..7
    int tile = i - bg * TILES;
    int n    = xcd + 8 * bg;

    int ty = tile / TX;
    int tx = tile - ty * TX;
    // overlapped border tiles: every tile fully inside the output
    int w0 = min(tx * TW, W_ - TW);            // 424 for tx=14
    int h0 = min(ty * TH, H_ - TH);            // 313 for ty=10

    const float* t = theta + n * 6;
    float t00 = ufl(t[0]), t01 = ufl(t[1]), t02 = ufl(t[2]);
    float t10 = ufl(t[3]), t11 = ufl(t[4]), t12 = ufl(t[5]);

    const float halfW = 0.5f * (float)W_, cW = 0.5f * (float)(W_ - 1);
    const float halfH = 0.5f * (float)H_, cH = 0.5f * (float)(H_ - 1);
    const float startx = -(1.0f - 1.0f / (float)W_);
    const float starty = -(1.0f - 1.0f / (float)H_);

    // Linear map: ix = Ax*w + Bx*h + Cx ; iy = Ay*w + By*h + Cy
    float Ax = t00;
    float Bx = t01 * ((float)W_ / (float)H_);
    float Cx = fmaf(startx, t00, fmaf(starty, t01, t02)) * halfW + cW;
    float Ay = t10 * ((float)H_ / (float)W_);
    float By = t11;
    float Cy = fmaf(startx, t10, fmaf(starty, t11, t12)) * halfH + cH;

    // ---- exact source bbox over the tile (linear map, monotone) ----
    float ws = (float)w0, we = (float)(w0 + TW - 1);
    float hs = (float)h0, he = (float)(h0 + TH - 1);

    float xw0 = ws * Ax, xw1 = we * Ax;
    float xh0 = hs * Bx, xh1 = he * Bx;
    float minix = Cx + fminf(xw0, xw1) + fminf(xh0, xh1);
    float maxix = Cx + fmaxf(xw0, xw1) + fmaxf(xh0, xh1);

    float yw0 = ws * Ay, yw1 = we * Ay;
    float yh0 = hs * By, yh1 = he * By;
    float miniy = Cy + fminf(yw0, yw1) + fminf(yh0, yh1);
    float maxiy = Cy + fmaxf(yw0, yw1) + fmaxf(yh0, yh1);

    // +-1 margin (fp slack); +1 more on hi for bilinear's +1 corner
    int x_lo = (int)floorf(minix) - 1, x_hi = (int)floorf(maxix) + 2;
    int y_lo = (int)floorf(miniy) - 1, y_hi = (int)floorf(maxiy) + 2;

    int xa    = x_lo & ~3;                     // align down (ok for negatives)
    int cols4 = (x_hi - xa + 4) >> 2;
    int rows  = y_hi - y_lo + 1;
    bool fits = (cols4 <= CJ) && (rows <= RCAP);   // block-uniform

    const float* xn = x + (size_t)n * 3 * HW_;
    float* on = out + (size_t)n * 3 * HW_;

    int tid = threadIdx.x;
    int tw = (tid & 15) * 2, th = tid >> 4;    // th in 0..31
    int w = w0 + tw, h = h0 + th;

    if (__builtin_expect(fits, 1)) {
        // ---- stage 52 x rows window at (xa, y_lo); zero-fill OOI ----
        int nslots = 13 * rows;                // block-uniform (<= 650)
        bool interior = (xa >= 0) && (xa + 52 <= W_) &&
                        (y_lo >= 0) && (y_lo + rows <= H_);
        int s1 = tid;
        int r1 = s1 / 13, j1 = s1 - 13 * r1;
        int s2 = tid + 512;
        int r2 = s2 / 13, j2 = s2 - 13 * r2;
        bool do1 = s1 < nslots;
        bool do2 = s2 < nslots;

        if (interior) {
            if (do1) {
                const float* g1 = xn + (size_t)(y_lo + r1) * W_ + xa + 4 * j1;
                float4 a0 = *(const float4*)(g1);
                float4 a1 = *(const float4*)(g1 + HW_);
                float4 a2 = *(const float4*)(g1 + 2 * HW_);
                float* d1 = lds + 4 * s1;
                *(float4*)(d1)                 = a0;
                *(float4*)(d1 + CH_STRIDE)     = a1;
                *(float4*)(d1 + 2 * CH_STRIDE) = a2;
            }
            if (do2) {
                const float* g2 = xn + (size_t)(y_lo + r2) * W_ + xa + 4 * j2;
                float4 b0 = *(const float4*)(g2);
                float4 b1 = *(const float4*)(g2 + HW_);
                float4 b2 = *(const float4*)(g2 + 2 * HW_);
                float* d2 = lds + 4 * s2;
                *(float4*)(d2)                 = b0;
                *(float4*)(d2 + CH_STRIDE)     = b1;
                *(float4*)(d2 + 2 * CH_STRIDE) = b2;
            }
        } else {
            // edge staging: clamped (always-legal) float4 load + whole-granule select.
            // xa%4==0 and W%4==0 => each float4 granule is entirely in or out in x.
            if (do1) {
                int y  = y_lo + r1;
                int xc = xa + 4 * j1;
                int ycl = min(max(y, 0), H_ - 1);
                int xcl = min(max(xc, 0), W_ - 4);
                bool valid = ((unsigned)y < (unsigned)H_) && ((unsigned)xc <= (unsigned)(W_ - 4));
                const float* g1 = xn + (size_t)ycl * W_ + xcl;
                float4 a0 = *(const float4*)(g1);
                float4 a1 = *(const float4*)(g1 + HW_);
                float4 a2 = *(const float4*)(g1 + 2 * HW_);
                float4 z = make_float4(0.f, 0.f, 0.f, 0.f);
                if (!valid) { a0 = z; a1 = z; a2 = z; }
                float* d1 = lds + 4 * s1;
                *(float4*)(d1)                 = a0;
                *(float4*)(d1 + CH_STRIDE)     = a1;
                *(float4*)(d1 + 2 * CH_STRIDE) = a2;
            }
            if (do2) {
                int y  = y_lo + r2;
                int xc = xa + 4 * j2;
                int ycl = min(max(y, 0), H_ - 1);
                int xcl = min(max(xc, 0), W_ - 4);
                bool valid = ((unsigned)y < (unsigned)H_) && ((unsigned)xc <= (unsigned)(W_ - 4));
                const float* g2 = xn + (size_t)ycl * W_ + xcl;
                float4 b0 = *(const float4*)(g2);
                float4 b1 = *(const float4*)(g2 + HW_);
                float4 b2 = *(const float4*)(g2 + 2 * HW_);
                float4 z = make_float4(0.f, 0.f, 0.f, 0.f);
                if (!valid) { b0 = z; b1 = z; b2 = z; }
                float* d2 = lds + 4 * s2;
                *(float4*)(d2)                 = b0;
                *(float4*)(d2 + CH_STRIDE)     = b1;
                *(float4*)(d2 + 2 * CH_STRIDE) = b2;
            }
        }
        __syncthreads();

        // ---- compute: NO bounds or window checks (overlap tiles + bbox) ----
        float fw = (float)w, fh = (float)h;
        float hx  = fmaf(fh, Bx, Cx), hy = fmaf(fh, By, Cy);
        float ixA = fmaf(fw, Ax, hx), iyA = fmaf(fw, Ay, hy);
        float ixB = ixA + Ax,         iyB = iyA + Ay;

        float xfA = floorf(ixA), yfA = floorf(iyA);
        float fxA = ixA - xfA,   fyA = iyA - yfA;
        float xfB = floorf(ixB), yfB = floorf(iyB);
        float fxB = ixB - xfB,   fyB = iyB - yfB;

        int lcA = (int)xfA - xa, lrA = (int)yfA - y_lo;
        int lcB = (int)xfB - xa, lrB = (int)yfB - y_lo;

        const float* pA = lds + lrA * CCAP + lcA;
        const float* pB = lds + lrB * CCAP + lcB;
        f32x2 FX = {fxA, fxB};
        f32x2 FY = {fyA, fyB};

        size_t o = (size_t)h * W_ + w;

        // channel 0
        {
            f32x2 P00 = {pA[0],        pB[0]};
            f32x2 P10 = {pA[1],        pB[1]};
            f32x2 P01 = {pA[CCAP],     pB[CCAP]};
            f32x2 P11 = {pA[CCAP + 1], pB[CCAP + 1]};
            f32x2 top = (P10 - P00) * FX + P00;
            f32x2 bot = (P11 - P01) * FX + P01;
            f32x2 v   = (bot - top) * FY + top;
            __builtin_nontemporal_store(v, (f32x2*)(on + o));
        }
        // channel 1
        {
            f32x2 P00 = {pA[CH_STRIDE],            pB[CH_STRIDE]};
            f32x2 P10 = {pA[CH_STRIDE + 1],        pB[CH_STRIDE + 1]};
            f32x2 P01 = {pA[CH_STRIDE + CCAP],     pB[CH_STRIDE + CCAP]};
            f32x2 P11 = {pA[CH_STRIDE + CCAP + 1], pB[CH_STRIDE + CCAP + 1]};
            f32x2 top = (P10 - P00) * FX + P00;
            f32x2 bot = (P11 - P01) * FX + P01;
            f32x2 v   = (bot - top) * FY + top;
            __builtin_nontemporal_store(v, (f32x2*)(on + o + HW_));
        }
        // channel 2
        {
            f32x2 P00 = {pA[2 * CH_STRIDE],            pB[2 * CH_STRIDE]};
            f32x2 P10 = {pA[2 * CH_STRIDE + 1],        pB[2 * CH_STRIDE + 1]};
            f32x2 P01 = {pA[2 * CH_STRIDE + CCAP],     pB[2 * CH_STRIDE + CCAP]};
            f32x2 P11 = {pA[2 * CH_STRIDE + CCAP + 1], pB[2 * CH_STRIDE + CCAP + 1]};
            f32x2 top = (P10 - P00) * FX + P00;
            f32x2 bot = (P11 - P01) * FX + P01;
            f32x2 v   = (bot - top) * FY + top;
            __builtin_nontemporal_store(v, (f32x2*)(on + o + 2 * HW_));
        }
    } else {
        // ---- rare block-uniform wholesale path (theta-extreme): direct gather ----
        float fw = (float)w, fh = (float)h;
        float hx  = fmaf(fh, Bx, Cx), hy = fmaf(fh, By, Cy);
        float ixA = fmaf(fw, Ax, hx), iyA = fmaf(fw, Ay, hy);
        float ixB = ixA + Ax,         iyB = iyA + Ay;

        float xfA = floorf(ixA), yfA = floorf(iyA);
        float fxA = ixA - xfA,   fyA = iyA - yfA;
        int   XA  = (int)xfA,    YA  = (int)yfA;
        float xfB = floorf(ixB), yfB = floorf(iyB);
        float fxB = ixB - xfB,   fyB = iyB - yfB;
        int   XB  = (int)xfB,    YB  = (int)yfB;

        float gxA = 1.0f - fxA, gyA = 1.0f - fyA;
        float gxB = 1.0f - fxB, gyB = 1.0f - fyB;
        float wA00 = gxA * gyA, wA10 = fxA * gyA, wA01 = gxA * fyA, wA11 = fxA * fyA;
        float wB00 = gxB * gyB, wB10 = fxB * gyB, wB01 = gxB * fyB, wB11 = fxB * fyB;
        float vA0 = 0, vA1 = 0, vA2 = 0, vB0 = 0, vB1 = 0, vB2 = 0;
#define CORNG(xi, yi, wt, d0, d1, d2)                                         \
        if ((unsigned)(xi) < (unsigned)W_ && (unsigned)(yi) < (unsigned)H_) { \
            int off = (yi) * W_ + (xi);                                       \
            d0 += xn[off] * (wt);                                             \
            d1 += xn[HW_ + off] * (wt);                                       \
            d2 += xn[2 * HW_ + off] * (wt);                                   \
        }
        CORNG(XA,     YA,     wA00, vA0, vA1, vA2)
        CORNG(XA + 1, YA,     wA10, vA0, vA1, vA2)
        CORNG(XA,     YA + 1, wA01, vA0, vA1, vA2)
        CORNG(XA + 1, YA + 1, wA11, vA0, vA1, vA2)
        CORNG(XB,     YB,     wB00, vB0, vB1, vB2)
        CORNG(XB + 1, YB,     wB10, vB0, vB1, vB2)
        CORNG(XB,     YB + 1, wB01, vB0, vB1, vB2)
        CORNG(XB + 1, YB + 1, wB11, vB0, vB1, vB2)
#undef CORNG
        size_t o = (size_t)h * W_ + w;
        *(float2*)(on + o)           = make_float2(vA0, vB0);
        *(float2*)(on + o + HW_)     = make_float2(vA1, vB1);
        *(float2*)(on + o + 2 * HW_) = make_float2(vA2, vB2);
    }
}

extern "C" void kernel_launch(void* const* d_in, const int* in_sizes, int n_in,
                              void* d_out, int out_size, void* d_ws, size_t ws_size,
                              hipStream_t stream) {
    const float* x     = (const float*)d_in[0];
    const float* theta = (const float*)d_in[1];
    float* out = (float*)d_out;

    int blocks = N_ * TILES;   // 10560, divisible by 8
    gs_tiled<<<blocks, 512, 0, stream>>>(x, theta, out);
}

// Round 18
// 39.769 us; speedup vs baseline: 1.1401x; 1.1401x over previous
//
#include <hip/hip_runtime.h>

// affine_grid + grid_sample (bilinear, zeros, align_corners=False)
// N=64, C=3, H=345, W=456, fp32.
// Round 18: r15 structure verbatim + global_load_lds direct staging on the
//           interior path (removes VGPR round-trip + ds_write issue).
constexpr int N_ = 64, C_ = 3, H_ = 345, W_ = 456;
constexpr int HW_ = H_ * W_;

constexpr int TW = 32, TH = 16;                // output tile: 512 px, 2 px/thread
constexpr int TX = 15, TY = 22;
constexpr int TILES = TX * TY;                 // 330
constexpr int CCAP = 52;                       // staged cols / LDS row stride (13 float4)
constexpr int RCAP = 28;                       // staged rows capacity
constexpr int CJ   = 13;                       // float4 granules per row
constexpr int CH_STRIDE = RCAP * CCAP;         // 1456 floats/channel (17472 B total)

typedef __attribute__((ext_vector_type(2))) float f32x2;

__device__ __forceinline__ float ufl(float v) {
    return __int_as_float(__builtin_amdgcn_readfirstlane(__float_as_int(v)));
}

#define GLD_LDS16(gp, lp)                                                     \
    __builtin_amdgcn_global_load_lds(                                         \
        (const __attribute__((address_space(1))) void*)(gp),                  \
        (__attribute__((address_space(3))) void*)(lp), 16, 0, 0)

__global__ __launch_bounds__(256) void gs_tiled(
    const float* __restrict__ x,      // [N,3,H,W]
    const float* __restrict__ theta,  // [N,2,3]
    float* __restrict__ out)          // [N,3,H,W]
{
    __shared__ float lds[3 * CH_STRIDE];       // 17472 B -> 8 blocks/CU

    // XCD-affine: batch n -> XCD n%8 only (grid divisible by 8).
    int b    = blockIdx.x;
    int xcd  = b & 7;
    int i    = b >> 3;
    int bg   = i / TILES;
    int tile = i - bg * TILES;
    int n    = xcd + 8 * bg;

    int ty = tile / TX;
    int tx = tile - ty * TX;
    // overlapped border tiles: every tile fully inside the output
    int w0 = min(tx * TW, W_ - TW);
    int h0 = min(ty * TH, H_ - TH);

    const float* t = theta + n * 6;
    float t00 = ufl(t[0]), t01 = ufl(t[1]), t02 = ufl(t[2]);
    float t10 = ufl(t[3]), t11 = ufl(t[4]), t12 = ufl(t[5]);

    const float halfW = 0.5f * (float)W_, cW = 0.5f * (float)(W_ - 1);
    const float halfH = 0.5f * (float)H_, cH = 0.5f * (float)(H_ - 1);
    const float startx = -(1.0f - 1.0f / (float)W_);
    const float starty = -(1.0f - 1.0f / (float)H_);

    // Linear map: ix = Ax*w + Bx*h + Cx ; iy = Ay*w + By*h + Cy
    float Ax = t00;
    float Bx = t01 * ((float)W_ / (float)H_);
    float Cx = fmaf(startx, t00, fmaf(starty, t01, t02)) * halfW + cW;
    float Ay = t10 * ((float)H_ / (float)W_);
    float By = t11;
    float Cy = fmaf(startx, t10, fmaf(starty, t11, t12)) * halfH + cH;

    // ---- exact source bbox over the tile (linear map, monotone) ----
    float ws = (float)w0, we = (float)(w0 + TW - 1);
    float hs = (float)h0, he = (float)(h0 + TH - 1);

    float xw0 = ws * Ax, xw1 = we * Ax;
    float xh0 = hs * Bx, xh1 = he * Bx;
    float minix = Cx + fminf(xw0, xw1) + fminf(xh0, xh1);
    float maxix = Cx + fmaxf(xw0, xw1) + fmaxf(xh0, xh1);

    float yw0 = ws * Ay, yw1 = we * Ay;
    float yh0 = hs * By, yh1 = he * By;
    float miniy = Cy + fminf(yw0, yw1) + fminf(yh0, yh1);
    float maxiy = Cy + fmaxf(yw0, yw1) + fmaxf(yh0, yh1);

    // +-1 margin (fp slack); +1 more on hi for bilinear's +1 corner
    int x_lo = (int)floorf(minix) - 1, x_hi = (int)floorf(maxix) + 2;
    int y_lo = (int)floorf(miniy) - 1, y_hi = (int)floorf(maxiy) + 2;

    int xa    = x_lo & ~3;                     // align down (ok for negatives)
    int cols4 = (x_hi - xa + 4) >> 2;
    int rows  = y_hi - y_lo + 1;
    bool fits = (cols4 <= CJ) && (rows <= RCAP);   // block-uniform

    const float* xn = x + (size_t)n * 3 * HW_;
    float* on = out + (size_t)n * 3 * HW_;

    int tid = threadIdx.x;
    int tw = (tid & 15) * 2, th = tid >> 4;
    int w = w0 + tw, h = h0 + th;

    if (__builtin_expect(fits, 1)) {
        // ---- stage 52 x rows window at (xa, y_lo); zero-fill OOI ----
        int nslots = 13 * rows;                // block-uniform slot count
        bool interior = (xa >= 0) && (xa + 52 <= W_) &&
                        (y_lo >= 0) && (y_lo + rows <= H_);
        int s1 = tid;
        int r1 = s1 / 13, j1 = s1 - 13 * r1;
        int s2 = tid + 256;
        int r2 = s2 / 13, j2 = s2 - 13 * r2;
        bool do1 = s1 < nslots;
        bool do2 = s2 < nslots;

        if (interior) {
            // direct global->LDS staging (no VGPR round-trip, no ds_write)
            if (do1) {
                const float* g1 = xn + (size_t)(y_lo + r1) * W_ + xa + 4 * j1;
                float* d1 = lds + 4 * s1;
                GLD_LDS16(g1,            d1);
                GLD_LDS16(g1 + HW_,      d1 + CH_STRIDE);
                GLD_LDS16(g1 + 2 * HW_,  d1 + 2 * CH_STRIDE);
            }
            if (do2) {
                const float* g2 = xn + (size_t)(y_lo + r2) * W_ + xa + 4 * j2;
                float* d2 = lds + 4 * s2;
                GLD_LDS16(g2,            d2);
                GLD_LDS16(g2 + HW_,      d2 + CH_STRIDE);
                GLD_LDS16(g2 + 2 * HW_,  d2 + 2 * CH_STRIDE);
            }
        } else {
            // edge staging: clamped (always-legal) float4 load + whole-granule select.
            // xa%4==0 and W%4==0 => each float4 granule is entirely in or out in x.
            if (do1) {
                int y  = y_lo + r1;
                int xc = xa + 4 * j1;
                int ycl = min(max(y, 0), H_ - 1);
                int xcl = min(max(xc, 0), W_ - 4);
                bool valid = ((unsigned)y < (unsigned)H_) && ((unsigned)xc <= (unsigned)(W_ - 4));
                const float* g1 = xn + (size_t)ycl * W_ + xcl;
                float4 a0 = *(const float4*)(g1);
                float4 a1 = *(const float4*)(g1 + HW_);
                float4 a2 = *(const float4*)(g1 + 2 * HW_);
                float4 z = make_float4(0.f, 0.f, 0.f, 0.f);
                if (!valid) { a0 = z; a1 = z; a2 = z; }
                float* d1 = lds + 4 * s1;
                *(float4*)(d1)                 = a0;
                *(float4*)(d1 + CH_STRIDE)     = a1;
                *(float4*)(d1 + 2 * CH_STRIDE) = a2;
            }
            if (do2) {
                int y  = y_lo + r2;
                int xc = xa + 4 * j2;
                int ycl = min(max(y, 0), H_ - 1);
                int xcl = min(max(xc, 0), W_ - 4);
                bool valid = ((unsigned)y < (unsigned)H_) && ((unsigned)xc <= (unsigned)(W_ - 4));
                const float* g2 = xn + (size_t)ycl * W_ + xcl;
                float4 b0 = *(const float4*)(g2);
                float4 b1 = *(const float4*)(g2 + HW_);
                float4 b2 = *(const float4*)(g2 + 2 * HW_);
                float4 z = make_float4(0.f, 0.f, 0.f, 0.f);
                if (!valid) { b0 = z; b1 = z; b2 = z; }
                float* d2 = lds + 4 * s2;
                *(float4*)(d2)                 = b0;
                *(float4*)(d2 + CH_STRIDE)     = b1;
                *(float4*)(d2 + 2 * CH_STRIDE) = b2;
            }
        }
        __syncthreads();                       // drains vmcnt (incl. load_lds) + lgkmcnt

        // ---- compute: NO bounds or window checks (overlap tiles + bbox) ----
        float fw = (float)w, fh = (float)h;
        float hx  = fmaf(fh, Bx, Cx), hy = fmaf(fh, By, Cy);
        float ixA = fmaf(fw, Ax, hx), iyA = fmaf(fw, Ay, hy);
        float ixB = ixA + Ax,         iyB = iyA + Ay;

        float xfA = floorf(ixA), yfA = floorf(iyA);
        float fxA = ixA - xfA,   fyA = iyA - yfA;
        float xfB = floorf(ixB), yfB = floorf(iyB);
        float fxB = ixB - xfB,   fyB = iyB - yfB;

        int lcA = (int)xfA - xa, lrA = (int)yfA - y_lo;
        int lcB = (int)xfB - xa, lrB = (int)yfB - y_lo;

        const float* pA = lds + lrA * CCAP + lcA;
        const float* pB = lds + lrB * CCAP + lcB;
        f32x2 FX = {fxA, fxB};
        f32x2 FY = {fyA, fyB};

        size_t o = (size_t)h * W_ + w;

        // channel 0
        {
            f32x2 P00 = {pA[0],        pB[0]};
            f32x2 P10 = {pA[1],        pB[1]};
            f32x2 P01 = {pA[CCAP],     pB[CCAP]};
            f32x2 P11 = {pA[CCAP + 1], pB[CCAP + 1]};
            f32x2 top = (P10 - P00) * FX + P00;
            f32x2 bot = (P11 - P01) * FX + P01;
            f32x2 v   = (bot - top) * FY + top;
            *(float2*)(on + o) = make_float2(v.x, v.y);
        }
        // channel 1
        {
            f32x2 P00 = {pA[CH_STRIDE],            pB[CH_STRIDE]};
            f32x2 P10 = {pA[CH_STRIDE + 1],        pB[CH_STRIDE + 1]};
            f32x2 P01 = {pA[CH_STRIDE + CCAP],     pB[CH_STRIDE + CCAP]};
            f32x2 P11 = {pA[CH_STRIDE + CCAP + 1], pB[CH_STRIDE + CCAP + 1]};
            f32x2 top = (P10 - P00) * FX + P00;
            f32x2 bot = (P11 - P01) * FX + P01;
            f32x2 v   = (bot - top) * FY + top;
            *(float2*)(on + o + HW_) = make_float2(v.x, v.y);
        }
        // channel 2
        {
            f32x2 P00 = {pA[2 * CH_STRIDE],            pB[2 * CH_STRIDE]};
            f32x2 P10 = {pA[2 * CH_STRIDE + 1],        pB[2 * CH_STRIDE + 1]};
            f32x2 P01 = {pA[2 * CH_STRIDE + CCAP],     pB[2 * CH_STRIDE + CCAP]};
            f32x2 P11 = {pA[2 * CH_STRIDE + CCAP + 1], pB[2 * CH_STRIDE + CCAP + 1]};
            f32x2 top = (P10 - P00) * FX + P00;
            f32x2 bot = (P11 - P01) * FX + P01;
            f32x2 v   = (bot - top) * FY + top;
            *(float2*)(on + o + 2 * HW_) = make_float2(v.x, v.y);
        }
    } else {
        // ---- rare block-uniform wholesale path (theta-extreme): direct gather ----
        float fw = (float)w, fh = (float)h;
        float hx  = fmaf(fh, Bx, Cx), hy = fmaf(fh, By, Cy);
        float ixA = fmaf(fw, Ax, hx), iyA = fmaf(fw, Ay, hy);
        float ixB = ixA + Ax,         iyB = iyA + Ay;

        float xfA = floorf(ixA), yfA = floorf(iyA);
        float fxA = ixA - xfA,   fyA = iyA - yfA;
        int   XA  = (int)xfA,    YA  = (int)yfA;
        float xfB = floorf(ixB), yfB = floorf(iyB);
        float fxB = ixB - xfB,   fyB = iyB - yfB;
        int   XB  = (int)xfB,    YB  = (int)yfB;

        float gxA = 1.0f - fxA, gyA = 1.0f - fyA;
        float gxB = 1.0f - fxB, gyB = 1.0f - fyB;
        float wA00 = gxA * gyA, wA10 = fxA * gyA, wA01 = gxA * fyA, wA11 = fxA * fyA;
        float wB00 = gxB * gyB, wB10 = fxB * gyB, wB01 = gxB * fyB, wB11 = fxB * fyB;
        float vA0 = 0, vA1 = 0, vA2 = 0, vB0 = 0, vB1 = 0, vB2 = 0;
#define CORNG(xi, yi, wt, d0, d1, d2)                                         \
        if ((unsigned)(xi) < (unsigned)W_ && (unsigned)(yi) < (unsigned)H_) { \
            int off = (yi) * W_ + (xi);                                       \
            d0 += xn[off] * (wt);                                             \
            d1 += xn[HW_ + off] * (wt);                                       \
            d2 += xn[2 * HW_ + off] * (wt);                                   \
        }
        CORNG(XA,     YA,     wA00, vA0, vA1, vA2)
        CORNG(XA + 1, YA,     wA10, vA0, vA1, vA2)
        CORNG(XA,     YA + 1, wA01, vA0, vA1, vA2)
        CORNG(XA + 1, YA + 1, wA11, vA0, vA1, vA2)
        CORNG(XB,     YB,     wB00, vB0, vB1, vB2)
        CORNG(XB + 1, YB,     wB10, vB0, vB1, vB2)
        CORNG(XB,     YB + 1, wB01, vB0, vB1, vB2)
        CORNG(XB + 1, YB + 1, wB11, vB0, vB1, vB2)
#undef CORNG
        size_t o = (size_t)h * W_ + w;
        *(float2*)(on + o)           = make_float2(vA0, vB0);
        *(float2*)(on + o + HW_)     = make_float2(vA1, vB1);
        *(float2*)(on + o + 2 * HW_) = make_float2(vA2, vB2);
    }
}

extern "C" void kernel_launch(void* const* d_in, const int* in_sizes, int n_in,
                              void* d_out, int out_size, void* d_ws, size_t ws_size,
                              hipStream_t stream) {
    const float* x     = (const float*)d_in[0];
    const float* theta = (const float*)d_in[1];
    float* out = (float*)d_out;

    int blocks = N_ * TILES;   // 21120, divisible by 8
    gs_tiled<<<blocks, 256, 0, stream>>>(x, theta, out);
}